// Round 9
// baseline (44.404 us; speedup 1.0000x reference)
//
#include <hip/hip_runtime.h>
#include <hip/hip_bf16.h>

typedef __attribute__((ext_vector_type(8))) short short8;
typedef __attribute__((ext_vector_type(4))) short short4v;
typedef __attribute__((ext_vector_type(4))) float floatx4;
typedef __attribute__((ext_vector_type(4))) int intx4;
typedef unsigned int u32;
typedef unsigned short u16;

#define NB 1024
#define ND 16
#define NM 4
#define NR 4096
#define NC 64
#define EPSF 1e-9f
#define PADK 4112  // 4096 + 16: row shift = 8 banks -> conflict-free A-frag reads

__device__ inline u16 f2bf(float f) {
    u32 u;
    __builtin_memcpy(&u, &f, 4);
    u32 lsb = (u >> 16) & 1;
    u += 0x7fffu + lsb;   // round-to-nearest-even
    return (u16)(u >> 16);
}
__device__ inline float bf2f(u16 v) {
    u32 u = ((u32)v) << 16;
    float f;
    __builtin_memcpy(&f, &u, 4);
    return f;
}

// ---- Kernel 1: blocks 0..255 cons-reduce -> s_consT[c][r]; blocks 256..271 pack rules ----
__global__ __launch_bounds__(256) void k_prep(const float* __restrict__ cons,
                                              const int* __restrict__ rules,
                                              u16* __restrict__ s_consT,
                                              u32* __restrict__ packed) {
    __shared__ u16 tile[16][68];
    int bid = blockIdx.x;
    int tid = threadIdx.x;
    if (bid >= 256) {
        int r = (bid - 256) * 256 + tid;
        const int* q = rules + (size_t)r * ND;
        u32 pk = 0;
#pragma unroll
        for (int i = 0; i < 4; ++i) {
            intx4 v = *(const intx4*)(q + i * 4);
#pragma unroll
            for (int e = 0; e < 4; ++e) pk |= ((u32)(v[e] & 3)) << (2 * (i * 4 + e));
        }
        packed[r] = pk;
        return;
    }
    int rbase = bid * 16;
    int c = tid & 63;
    int rr = tid >> 6;
#pragma unroll
    for (int it = 0; it < 4; ++it, rr += 4) {
        const float* p = cons + (size_t)(rbase + rr) * (ND + 1) * NC + c;
        float s = 0.f;
#pragma unroll
        for (int j = 0; j < ND + 1; ++j) s += p[j * NC];
        tile[rr][c] = f2bf(s);
    }
    __syncthreads();
    int cc = tid >> 2;
    int r0 = (tid & 3) * 4;
    short4v v;
#pragma unroll
    for (int e = 0; e < 4; ++e) v[e] = (short)tile[r0 + e][cc];
    *(short4v*)(s_consT + (size_t)cc * NR + rbase + r0) = v;
}

// ---- Kernel 2 (fused): per block = 4 batch rows: fs -> LDS -> nfs out + MFMA -> rule_out ----
__global__ __launch_bounds__(256) void k_fused(const float* __restrict__ x,
                                               const float* __restrict__ centers,
                                               const float* __restrict__ widths,
                                               const u32* __restrict__ packed,
                                               const u16* __restrict__ s_consT,
                                               float* __restrict__ out_nfs,
                                               float* __restrict__ out_xe,
                                               float* __restrict__ out_rule) {
    __shared__ __align__(16) u16 afrag[4][PADK];
    __shared__ float gtab4[4][1024];
    __shared__ float mftab[4][64];
    __shared__ float xv[4][16];
    __shared__ float rs[4];
    int b0 = blockIdx.x * 4;
    int tid = threadIdx.x;
    int w = tid >> 6, lane = tid & 63;

    if (tid < 64) xv[tid >> 4][tid & 15] = x[b0 * 16 + tid];
    if (tid < 68) {
        int bb = tid / 17, ii = tid % 17;
        out_xe[(size_t)(b0 + bb) * 17 + ii] = (ii < 16) ? x[(b0 + bb) * 16 + ii] : 1.0f;
    }
    __syncthreads();
    {   // 256 membership values: b = tid>>6, (d,m) = tid&63
        int bb = tid >> 6, dm = tid & 63;
        float diff = xv[bb][dm >> 2] - centers[dm];
        float wd = widths[dm];
        mftab[bb][dm] = __expf(-diff * diff / (2.f * wd * wd)) + EPSF;
    }
    __syncthreads();
    // 4 b-rows x 4 groups x 256-entry product tables
#pragma unroll
    for (int it = 0; it < 16; ++it) {
        int idx = it * 256 + tid;
        int bb = idx >> 10, rest = idx & 1023, g = rest >> 8, i = rest & 255;
        const float* mf = &mftab[bb][g * 16];
        gtab4[bb][g * 256 + i] = mf[i & 3] * mf[4 + ((i >> 2) & 3)] *
                                 mf[8 + ((i >> 4) & 3)] * mf[12 + ((i >> 6) & 3)];
    }
    __syncthreads();
    // wave w owns batch row b0+w : fs + row sum
    const float* gt = gtab4[w];
    float lsum = 0.f;
#pragma unroll 4
    for (int it = 0; it < 64; ++it) {
        int r = it * 64 + lane;
        u32 pk = packed[r];
        float f = gt[pk & 255] * gt[256 + ((pk >> 8) & 255)] *
                  gt[512 + ((pk >> 16) & 255)] * gt[768 + (pk >> 24)];
        afrag[w][r] = f2bf(f);
        lsum += f;
    }
#pragma unroll
    for (int off = 32; off; off >>= 1) lsum += __shfl_xor(lsum, off, 64);
    float inv = 1.f / (lsum + EPSF);
    if (lane == 0) {
        float s = 1.f;
#pragma unroll
        for (int i = 0; i < 16; ++i) s += xv[w][i];
        rs[w] = s * inv;   // (1 + sum x) / den : epilogue scale
    }
    // normalized nfs (fp32) from bf16 fs
    float* on = out_nfs + (size_t)(b0 + w) * NR;
#pragma unroll
    for (int it = 0; it < 16; ++it) {
        int r = it * 256 + lane * 4;
        short4v v4 = *(const short4v*)&afrag[w][r];
        floatx4 o;
#pragma unroll
        for (int e = 0; e < 4; ++e) o[e] = bf2f((u16)v4[e]) * inv;
        *(floatx4*)(on + r) = o;
    }
    __syncthreads();
    // GEMM: wave w -> cols [16w,16w+16), rows b0..b0+3 (A rows 4..15 are zero)
    int col = w * 16 + (lane & 15);
    int row = lane & 15;
    int ks = lane >> 4;
    const u16* bptr = s_consT + (size_t)col * NR + ks * 8;
    const u16* aptr = &afrag[row < 4 ? row : 0][ks * 8];
    bool arow_ok = row < 4;
    floatx4 acc = {};
#pragma unroll 4
    for (int kt = 0; kt < NR / 32; ++kt) {
        short8 bf = *(const short8*)(bptr + kt * 32);
        short8 af = {};
        if (arow_ok) af = *(const short8*)(aptr + kt * 32);
        acc = __builtin_amdgcn_mfma_f32_16x16x32_bf16(af, bf, acc, 0, 0, 0);
    }
    if (lane < 16) {
#pragma unroll
        for (int reg = 0; reg < 4; ++reg)
            out_rule[(size_t)(b0 + reg) * NC + col] = acc[reg] * rs[reg];
    }
}

extern "C" void kernel_launch(void* const* d_in, const int* in_sizes, int n_in,
                              void* d_out, int out_size, void* d_ws, size_t ws_size,
                              hipStream_t stream) {
    const float* x = (const float*)d_in[0];
    const float* centers = (const float*)d_in[1];
    const float* widths = (const float*)d_in[2];
    const float* cons = (const float*)d_in[3];
    const int* rules = (const int*)d_in[4];

    float* out = (float*)d_out;
    float* out_rule = out;                        // [1024,64]
    float* out_nfs = out + NB * NC;               // [1024,4096]
    float* out_xe = out + NB * NC + NB * NR;      // [1024,17]

    char* ws = (char*)d_ws;
    u16* s_consT = (u16*)ws;                      // 512 KB
    u32* packed = (u32*)(ws + (512 << 10));       // 16 KB

    k_prep<<<272, 256, 0, stream>>>(cons, rules, s_consT, packed);
    k_fused<<<NB / 4, 256, 0, stream>>>(x, centers, widths, packed, s_consT,
                                        out_nfs, out_xe, out_rule);
}